// Round 1
// baseline (75.186 us; speedup 1.0000x reference)
//
#include <hip/hip_runtime.h>

// QConv2D quanvolution: 4-qubit statevector sim per 2x2 patch.
// x: (32,1,128,128) fp32; params: (2,4,2) fp32; out: (32,4,127,127) fp32.
// One thread per patch; 16-amplitude complex state held in registers.
// Wire w <-> bit (8>>w) because state index = q0*8+q1*4+q2*2+q3.

#define HH 128
#define WW 128
#define HO 127
#define WO 127
#define BB 32

// RX(theta) on wire with mask M: new = c*psi - i*s*psi_flipped
template <int M>
__device__ __forceinline__ void rx_gate(float* re, float* im, float th) {
    float s, c;
    __sincosf(th * 0.5f, &s, &c);
#pragma unroll
    for (int idx = 0; idx < 16; ++idx) {
        if (idx & M) continue;          // folds at compile time (M is template)
        const int p = idx | M;
        float r0 = re[idx], i0 = im[idx], r1 = re[p], i1 = im[p];
        re[idx] = fmaf(c, r0, s * i1);
        im[idx] = fmaf(c, i0, -s * r1);
        re[p]   = fmaf(c, r1, s * i0);
        im[p]   = fmaf(c, i1, -s * r0);
    }
}

// RZ(theta): bit==0 -> e^{-i th/2}, bit==1 -> e^{+i th/2}
template <int M>
__device__ __forceinline__ void rz_gate(float* re, float* im, float th) {
    float sp, cp;
    __sincosf(th * 0.5f, &sp, &cp);
#pragma unroll
    for (int idx = 0; idx < 16; ++idx) {
        float r = re[idx], q = im[idx];
        if (idx & M) {
            re[idx] = fmaf(r, cp, -q * sp);
            im[idx] = fmaf(q, cp, r * sp);
        } else {
            re[idx] = fmaf(r, cp, q * sp);
            im[idx] = fmaf(q, cp, -r * sp);
        }
    }
}

// CNOT: when control bit set, swap target-bit pair. Pure register rename.
template <int CM, int TM>
__device__ __forceinline__ void cnot_gate(float* re, float* im) {
#pragma unroll
    for (int idx = 0; idx < 16; ++idx) {
        if ((idx & CM) && !(idx & TM)) {
            const int p = idx | TM;
            float t;
            t = re[idx]; re[idx] = re[p]; re[p] = t;
            t = im[idx]; im[idx] = im[p]; im[p] = t;
        }
    }
}

__global__ __launch_bounds__(256) void qconv_kernel(
    const float* __restrict__ x, const float* __restrict__ prm,
    float* __restrict__ out, int total) {
    int tid = blockIdx.x * blockDim.x + threadIdx.x;
    if (tid >= total) return;

    int j = tid % WO;
    int t = tid / WO;
    int i = t % HO;
    int b = t / HO;

    const float* xp = x + ((size_t)b * HH + i) * WW + j;
    // patch flatten order (C, kh, kw): a[kh*2+kw] = x[b,0,i+kh,j+kw]
    float a0 = xp[0], a1 = xp[1], a2 = xp[WW], a3 = xp[WW + 1];

    float re[16], im[16];
#pragma unroll
    for (int k = 0; k < 16; ++k) { re[k] = 0.f; im[k] = 0.f; }
    re[0] = 1.0f;

    // AngleEmbedding: RX(x_w) on wire w
    rx_gate<8>(re, im, a0);
    rx_gate<4>(re, im, a1);
    rx_gate<2>(re, im, a2);
    rx_gate<1>(re, im, a3);

    // 2 layers: per-wire RX,RZ then CNOT chain (ctrl=w+1, tgt=w)
#pragma unroll
    for (int l = 0; l < 2; ++l) {
        const float* p = prm + l * 8;  // params[l][w][k] = prm[l*8 + w*2 + k]
        rx_gate<8>(re, im, p[0]); rz_gate<8>(re, im, p[1]);
        rx_gate<4>(re, im, p[2]); rz_gate<4>(re, im, p[3]);
        rx_gate<2>(re, im, p[4]); rz_gate<2>(re, im, p[5]);
        rx_gate<1>(re, im, p[6]); rz_gate<1>(re, im, p[7]);
        cnot_gate<4, 8>(re, im);  // CNOT(1,0)
        cnot_gate<2, 4>(re, im);  // CNOT(2,1)
        cnot_gate<1, 2>(re, im);  // CNOT(3,2)
    }

    // <Z_w> = sum_idx |amp|^2 * (bit w ? -1 : +1)
    float z0 = 0.f, z1 = 0.f, z2 = 0.f, z3 = 0.f;
#pragma unroll
    for (int idx = 0; idx < 16; ++idx) {
        float pr = fmaf(re[idx], re[idx], im[idx] * im[idx]);
        z0 += (idx & 8) ? -pr : pr;
        z1 += (idx & 4) ? -pr : pr;
        z2 += (idx & 2) ? -pr : pr;
        z3 += (idx & 1) ? -pr : pr;
    }

    // out[b, w, i, j], strides: w-stride = HO*WO
    float* o = out + (((size_t)b * 4) * HO + (size_t)i) * WO + j;
    o[0]            = z0;
    o[HO * WO]      = z1;
    o[2 * HO * WO]  = z2;
    o[3 * HO * WO]  = z3;
}

extern "C" void kernel_launch(void* const* d_in, const int* in_sizes, int n_in,
                              void* d_out, int out_size, void* d_ws, size_t ws_size,
                              hipStream_t stream) {
    const float* x = (const float*)d_in[0];
    const float* prm = (const float*)d_in[1];
    float* out = (float*)d_out;
    const int total = BB * HO * WO;  // 516128 patches
    const int blocks = (total + 255) / 256;
    qconv_kernel<<<blocks, 256, 0, stream>>>(x, prm, out, total);
}